// Round 15
// baseline (351.791 us; speedup 1.0000x reference)
//
#include <hip/hip_runtime.h>
#include <hip/hip_bf16.h>
#include <hip/hip_fp16.h>

// Problem: B=32, T=256, I=128, H=128, C=100. All fp32.
// Structure (r15): 2 dispatches.
//  1. gemm_prep: G = x @ W_ih^T + bias (MFMA split-bf16, in-register W
//     conversion) + packing of whh_h (f16-pair dot2 layout) and W2v.
//  2. lstm_fused: recurrence via v_dot2_f32_f16 + in-block attention tail.
//
// r15 recurrence redesign: the 201us wall was ~1080 issue cyc/SIMD/step =
// 64 pk_fma + 128 v_accvgpr_read (AGPR copy tax: 128 f32 weights/thread
// can't fit the allocator's 84-VGPR choice; no VALU op sources AGPRs, r4
// assembler proof) + ~70 misc. Fix: weights as f16 PAIRS = 64 VGPRs/thread
// (fits!), consumed by v_dot2_f32_f16 (2 MACs/instr, f32 accum). h keeps
// ~f32 precision via f16 hi/lo split in LDS (2 dot2 per pair). New error
// source: W quantized to f16 (2^-11 rel) -- fixed perturbed W', contractive
// gates. 128 dot2 + 8 ds_read_b128 + misc ~= 790 issue cyc vs 1080.

#define Bsz 32
#define Tsz 256
#define Isz 128
#define Hsz 128
#define Csz 100
#define G4H 512   // 4*H

typedef short v8s __attribute__((ext_vector_type(8)));   // 8 bf16 = 4 VGPRs
typedef float v4fa __attribute__((ext_vector_type(4)));  // MFMA acc
typedef _Float16 h2 __attribute__((ext_vector_type(2))); // packed f16 pair

__device__ __forceinline__ h2 as_h2(unsigned u) {
    union { unsigned u; h2 h; } x; x.u = u; return x.h;
}
__device__ __forceinline__ float fdot2(unsigned w, unsigned h, float c) {
    return __builtin_amdgcn_fdot2(as_h2(w), as_h2(h), c, false);
}
__device__ __forceinline__ float quad_rsum(float x) {
    int t = __builtin_amdgcn_update_dpp(0, __float_as_int(x), 0xB1, 0xF, 0xF, true); // xor 1
    x += __int_as_float(t);
    t = __builtin_amdgcn_update_dpp(0, __float_as_int(x), 0x4E, 0xF, 0xF, true);     // xor 2
    x += __int_as_float(t);
    return x;
}
__device__ __forceinline__ float oct_rsum(float x) {
    int t = __builtin_amdgcn_update_dpp(0, __float_as_int(x), 0xB1, 0xF, 0xF, true);
    x += __int_as_float(t);
    t = __builtin_amdgcn_update_dpp(0, __float_as_int(x), 0x4E, 0xF, 0xF, true);
    x += __int_as_float(t);
    t = __builtin_amdgcn_update_dpp(0, __float_as_int(x), 0x141, 0xF, 0xF, true);
    x += __int_as_float(t);
    return x;
}
__device__ __forceinline__ float rcpf(float x) { return __builtin_amdgcn_rcpf(x); }
__device__ __forceinline__ float ex2(float x) { return __builtin_amdgcn_exp2f(x); }
__device__ __forceinline__ float sigm_n(float x) {
    return rcpf(1.0f + ex2(-1.442695041f * x));
}
__device__ __forceinline__ float tanh_n(float x) {
    return fmaf(-2.0f, rcpf(1.0f + ex2(2.885390082f * x)), 1.0f);
}
__device__ __forceinline__ short bf16_bits(float x) {
    __hip_bfloat16 h = __float2bfloat16(x);
    return *reinterpret_cast<short*>(&h);
}
__device__ __forceinline__ float bf16_val(float x) {
    return __bfloat162float(__float2bfloat16(x));
}
__device__ __forceinline__ unsigned short f16_bits(float x) {
    __half h = __float2half(x);
    return *reinterpret_cast<unsigned short*>(&h);
}

// ---------------- kernel 1: fused gemmG + prep ----------------
// blocks < 1024: one 64x64 tile of G = x @ w_ih^T + (b_ih + b_hh).
// blocks >= 1024: pack whh_h (f16-pair dot2 layout, 32768 u32) + W2v.
__global__ __launch_bounds__(256) void gemm_prep(
    const float* __restrict__ x, const float* __restrict__ w_ih,
    const float* __restrict__ b_ih, const float* __restrict__ w_hh,
    const float* __restrict__ b_hh, const float* __restrict__ w1,
    __hip_bfloat16* __restrict__ W2v, unsigned* __restrict__ whh_h,
    float* __restrict__ G) {
    const int bid = blockIdx.x;
    const int tid = threadIdx.x;

    if (bid >= 1024) {
        int idx = (bid - 1024) * 256 + tid;        // 0..49151
        if (idx < 32768) {
            // whh_h[f*2048 + t*4 + c]: thread t=(d*4+q), frame f=(j4*4+g),
            // component c -> f16 pair (w[g*128+d][k0], [k0+1]), k0=q*32+8*j4+2c
            int c  = idx & 3;
            int t  = (idx >> 2) & 511;
            int f  = idx >> 11;
            int d  = t >> 2;
            int q  = t & 3;
            int g  = f & 3;
            int j4 = f >> 2;
            int k0 = q * 32 + 8 * j4 + 2 * c;
            const float* wr = w_hh + (size_t)((g << 7) + d) * 128 + k0;
            unsigned lo = f16_bits(wr[0]);
            unsigned hi = f16_bits(wr[1]);
            whh_h[idx] = lo | (hi << 16);
        } else if (idx < 32768 + 16384) {
            int t = idx - 32768;
            int n = t >> 7;            // output col of KV
            int k = t & 127;
            float v = w1[(size_t)(128 + k) * Hsz + n];
            __hip_bfloat16 hi = __float2bfloat16(v);
            __hip_bfloat16 lo = __float2bfloat16(v - __bfloat162float(hi));
            W2v[(size_t)n * 384 + k] = hi;
            W2v[(size_t)n * 384 + 128 + k] = lo;
            W2v[(size_t)n * 384 + 256 + k] = hi;
        }
        return;
    }

    // ---- gemmG tile: m-tile = bid>>3, n-tile = bid&7
    const int w = tid >> 6, lane = tid & 63;
    const int m0 = (bid >> 3) * 64 + (w & 1) * 32;
    const int n0 = (bid & 7) * 64 + (w >> 1) * 32;
    const int r = lane & 15, quad = lane >> 4;

    v8s Ahi[2][4], Alo[2][4];
    #pragma unroll
    for (int i = 0; i < 2; ++i)
        #pragma unroll
        for (int cb = 0; cb < 4; ++cb) {
            const float* src = x + (size_t)(m0 + 16 * i + r) * Isz + cb * 32 + quad * 8;
            float4 f0 = *(const float4*)src;
            float4 f1 = *(const float4*)(src + 4);
            float f[8] = {f0.x, f0.y, f0.z, f0.w, f1.x, f1.y, f1.z, f1.w};
            v8s hi, lo;
            #pragma unroll
            for (int e = 0; e < 8; ++e) {
                float hv = bf16_val(f[e]);
                hi[e] = bf16_bits(f[e]);
                lo[e] = bf16_bits(f[e] - hv);
            }
            Ahi[i][cb] = hi;
            Alo[i][cb] = lo;
        }

    v8s Bhi[2][4], Blo[2][4];
    #pragma unroll
    for (int j = 0; j < 2; ++j)
        #pragma unroll
        for (int cb = 0; cb < 4; ++cb) {
            const float* src = w_ih + (size_t)(n0 + 16 * j + r) * Isz + cb * 32 + quad * 8;
            float4 f0 = *(const float4*)src;
            float4 f1 = *(const float4*)(src + 4);
            float f[8] = {f0.x, f0.y, f0.z, f0.w, f1.x, f1.y, f1.z, f1.w};
            v8s hi, lo;
            #pragma unroll
            for (int e = 0; e < 8; ++e) {
                float hv = bf16_val(f[e]);
                hi[e] = bf16_bits(f[e]);
                lo[e] = bf16_bits(f[e] - hv);
            }
            Bhi[j][cb] = hi;
            Blo[j][cb] = lo;
        }

    v4fa acc[2][2] = {};
    #pragma unroll
    for (int ks = 0; ks < 12; ++ks) {
        int cb = ks & 3;
        bool blo = (ks >= 4) && (ks < 8);
        v8s a0 = (ks >= 8) ? Alo[0][cb] : Ahi[0][cb];
        v8s a1 = (ks >= 8) ? Alo[1][cb] : Ahi[1][cb];
        v8s b0 = blo ? Blo[0][cb] : Bhi[0][cb];
        v8s b1 = blo ? Blo[1][cb] : Bhi[1][cb];
        acc[0][0] = __builtin_amdgcn_mfma_f32_16x16x32_bf16(a0, b0, acc[0][0], 0, 0, 0);
        acc[0][1] = __builtin_amdgcn_mfma_f32_16x16x32_bf16(a0, b1, acc[0][1], 0, 0, 0);
        acc[1][0] = __builtin_amdgcn_mfma_f32_16x16x32_bf16(a1, b0, acc[1][0], 0, 0, 0);
        acc[1][1] = __builtin_amdgcn_mfma_f32_16x16x32_bf16(a1, b1, acc[1][1], 0, 0, 0);
    }
    // C/D layout: col = lane&15, row = quad*4 + reg  [verified m89/m91]
    #pragma unroll
    for (int i = 0; i < 2; ++i)
        #pragma unroll
        for (int j = 0; j < 2; ++j) {
            int cn = n0 + 16 * j + r;
            float bb = b_ih[cn] + b_hh[cn];
            #pragma unroll
            for (int rr = 0; rr < 4; ++rr) {
                int row = m0 + 16 * i + quad * 4 + rr;
                G[(size_t)row * G4H + cn] = acc[i][j][rr] + bb;
            }
        }
}

// ---------------- kernel 2: dot2 LSTM + fused attention tail ----------------
__global__ __launch_bounds__(512, 2) void lstm_fused(
    const float* __restrict__ G, const unsigned* __restrict__ whh_h,
    const __hip_bfloat16* __restrict__ W2v,
    const float* __restrict__ w1, const float* __restrict__ w2,
    const float* __restrict__ w_fc, const float* __restrict__ b_fc,
    float* __restrict__ H_all, float* __restrict__ out) {
    const int b = blockIdx.x;
    const int tid = threadIdx.x;
    const int d = tid >> 2;
    const int q = tid & 3;

    __shared__ alignas(16) __half hhi_h[2][128];
    __shared__ alignas(16) __half hlo_h[2][128];
    __shared__ float kv_s[64][132];
    __shared__ float hT_s[Hsz];
    __shared__ float q_s[Hsz];
    __shared__ float w2s[Hsz];
    __shared__ float r_s[Hsz];
    __shared__ float s_s[64];
    __shared__ float part4[4][Hsz];

    // ===== recurrence: f16-pair weights (64 VGPRs), v_dot2_f32_f16 =====
    unsigned wf[16][4];   // [frame=j4*4+g][component c]; 64 u32
    {
        const uint4* wp = (const uint4*)whh_h;
        #pragma unroll
        for (int f = 0; f < 16; ++f) {
            uint4 v = wp[f * 512 + tid];
            wf[f][0] = v.x; wf[f][1] = v.y; wf[f][2] = v.z; wf[f][3] = v.w;
        }
    }

    if (tid < 128) {
        hhi_h[0][tid] = __float2half(0.0f); hhi_h[1][tid] = __float2half(0.0f);
        hlo_h[0][tid] = __float2half(0.0f); hlo_h[1][tid] = __float2half(0.0f);
    }
    float c = 0.0f;
    __syncthreads();

    const float* Gq = G + (size_t)b * Tsz * G4H + q * 128 + d;
    float* Hst = H_all + (size_t)b * Tsz * Hsz + d;

    float gval = Gq[0];
    int cur = 0;
    for (int t = 0; t < Tsz; ++t) {
        const int tn = (t < Tsz - 1) ? t + 1 : t;
        float ngval = Gq[(size_t)tn * G4H];   // prefetch; stays in flight

        float accH[4], accL[4];
        #pragma unroll
        for (int gi = 0; gi < 4; ++gi) {
            accH[gi] = (q == gi) ? gval : 0.f;
            accL[gi] = 0.f;
        }
        const uint4* hh4 = (const uint4*)&hhi_h[cur][0];
        const uint4* hl4 = (const uint4*)&hlo_h[cur][0];
        #pragma unroll
        for (int j4 = 0; j4 < 4; ++j4) {
            uint4 hh = hh4[q * 4 + j4];    // broadcast (same addr per q-group)
            uint4 hl = hl4[q * 4 + j4];
            unsigned hhc[4] = {hh.x, hh.y, hh.z, hh.w};
            unsigned hlc[4] = {hl.x, hl.y, hl.z, hl.w};
            #pragma unroll
            for (int cc = 0; cc < 4; ++cc) {
                #pragma unroll
                for (int g = 0; g < 4; ++g) {
                    accH[g] = fdot2(wf[j4 * 4 + g][cc], hhc[cc], accH[g]);
                    accL[g] = fdot2(wf[j4 * 4 + g][cc], hlc[cc], accL[g]);
                }
            }
        }
        float a0 = quad_rsum(accH[0] + accL[0]);
        float a1 = quad_rsum(accH[1] + accL[1]);
        float a2 = quad_rsum(accH[2] + accL[2]);
        float a3 = quad_rsum(accH[3] + accL[3]);

        float iv = sigm_n(a0);
        float fv = sigm_n(a1);
        float gv = tanh_n(a2);
        float ov = sigm_n(a3);
        c = fmaf(fv, c, iv * gv);
        float h = ov * tanh_n(c);

        if (q == 0) {
            __half hh16 = __float2half(h);
            hhi_h[cur ^ 1][d] = hh16;
            hlo_h[cur ^ 1][d] = __float2half(h - __half2float(hh16));
            Hst[(size_t)t * Hsz] = h;
        }
        gval = ngval;
        // raw barrier: wait LDS only, leave global load/store in flight
        __builtin_amdgcn_sched_barrier(0);
        asm volatile("s_waitcnt lgkmcnt(0)" ::: "memory");
        __builtin_amdgcn_s_barrier();
        __builtin_amdgcn_sched_barrier(0);
        cur ^= 1;
    }

    // ================= fused attention tail =================
    __syncthreads();   // full drain: H_all stores visible block-locally

    const float* Hb = H_all + (size_t)b * Tsz * Hsz;
    const int n_a = tid >> 2;

    // Phase A: stage hT (from H_all, exact f32) + w2; q_s = hT @ w1_top
    if (tid < Hsz) {
        hT_s[tid] = Hb[255 * Hsz + tid];
        w2s[tid] = w2[tid];
    }
    __syncthreads();
    {
        float acc = 0.f;
        #pragma unroll 8
        for (int kk = 0; kk < 32; ++kk) {
            int k = q * 32 + kk;
            acc = fmaf(hT_s[k], w1[(size_t)k * Hsz + n_a], acc);
        }
        acc = quad_rsum(acc);
        if (q == 0) q_s[n_a] = acc;
    }
    __syncthreads();

    // Phase B: 4 jt-tiles of 64 slots: KV (MFMA) -> scores -> attn partial
    const int w_id = tid >> 6;
    const int lane = tid & 63;
    const int fr = lane & 15, fq = lane >> 4;
    const int d_att = tid & 127, grp = tid >> 7;
    float racc = 0.f;

    for (int jt = 0; jt < 4; ++jt) {
        // B1: KV tile rows jt*64..+64, cols 0..128, 8 waves (one 32x32 each)
        {
            const int m0 = (w_id & 1) * 32;
            const int n0 = (w_id >> 1) * 32;
            const float* Abase = Hb + (size_t)(jt * 64) * Hsz;

            v8s Ahi[2][4], Alo[2][4];
            #pragma unroll
            for (int i = 0; i < 2; ++i)
                #pragma unroll
                for (int cb = 0; cb < 4; ++cb) {
                    const float* src = Abase + (size_t)(m0 + 16 * i + fr) * Hsz + cb * 32 + fq * 8;
                    float4 f0 = *(const float4*)src;
                    float4 f1 = *(const float4*)(src + 4);
                    float f[8] = {f0.x, f0.y, f0.z, f0.w, f1.x, f1.y, f1.z, f1.w};
                    v8s hi, lo;
                    #pragma unroll
                    for (int e = 0; e < 8; ++e) {
                        float hv = bf16_val(f[e]);
                        hi[e] = bf16_bits(f[e]);
                        lo[e] = bf16_bits(f[e] - hv);
                    }
                    Ahi[i][cb] = hi;
                    Alo[i][cb] = lo;
                }

            v4fa a2[2][2] = {};
            const short* Wb = (const short*)W2v;
            #pragma unroll
            for (int ks = 0; ks < 12; ++ks) {
                int cb = ks & 3;
                v8s a0 = (ks >= 8) ? Alo[0][cb] : Ahi[0][cb];
                v8s a1 = (ks >= 8) ? Alo[1][cb] : Ahi[1][cb];
                int kb = ks * 32 + fq * 8;
                v8s b0 = *(const v8s*)(Wb + (size_t)(n0 + fr) * 384 + kb);
                v8s b1 = *(const v8s*)(Wb + (size_t)(n0 + 16 + fr) * 384 + kb);
                a2[0][0] = __builtin_amdgcn_mfma_f32_16x16x32_bf16(a0, b0, a2[0][0], 0, 0, 0);
                a2[0][1] = __builtin_amdgcn_mfma_f32_16x16x32_bf16(a0, b1, a2[0][1], 0, 0, 0);
                a2[1][0] = __builtin_amdgcn_mfma_f32_16x16x32_bf16(a1, b0, a2[1][0], 0, 0, 0);
                a2[1][1] = __builtin_amdgcn_mfma_f32_16x16x32_bf16(a1, b1, a2[1][1], 0, 0, 0);
            }
            #pragma unroll
            for (int i = 0; i < 2; ++i)
                #pragma unroll
                for (int j = 0; j < 2; ++j)
                    #pragma unroll
                    for (int rr = 0; rr < 4; ++rr)
                        kv_s[m0 + 16 * i + fq * 4 + rr][n0 + 16 * j + fr] = a2[i][j][rr];
        }
        __syncthreads();

        // B2: scores, one 8-lane group per slot (64 slots)
        {
            const int jl = tid >> 3, oct = tid & 7;
            float p = 0.f;
            #pragma unroll
            for (int kk = 0; kk < 16; ++kk) {
                int k = oct * 16 + kk;
                p = fmaf(tanh_n(q_s[k] + kv_s[jl][k]), w2s[k], p);
            }
            p = oct_rsum(p);
            if (oct == 0) s_s[jl] = (jt * 64 + jl < 255) ? p : 0.0f;
        }
        __syncthreads();

        // B3: attn partial: racc += s[j] * H[j][d] over this tile's 16 j/grp
        #pragma unroll 4
        for (int u = 0; u < 16; ++u) {
            int lj = grp * 16 + u;
            racc = fmaf(s_s[lj], Hb[(size_t)(jt * 64 + lj) * Hsz + d_att], racc);
        }
        __syncthreads();   // protect kv_s / s_s before next jt overwrites
    }

    part4[grp][d_att] = racc;
    __syncthreads();
    if (tid < Hsz)
        r_s[tid] = hT_s[tid] + part4[0][tid] + part4[1][tid] + part4[2][tid] + part4[3][tid];
    __syncthreads();

    // Phase C: out[b] = r @ w_fc^T + b_fc (one quad per output)
    {
        const int o = tid >> 2;
        float acc = 0.f;
        if (o < Csz) {
            #pragma unroll 8
            for (int kk = 0; kk < 32; ++kk) {
                int k = q * 32 + kk;
                acc = fmaf(r_s[k], w_fc[(size_t)o * Hsz + k], acc);
            }
        }
        acc = quad_rsum(acc);
        if (q == 0 && o < Csz) out[b * Csz + o] = acc + b_fc[o];
    }
}

// ---------------- launch ----------------
extern "C" void kernel_launch(void* const* d_in, const int* in_sizes, int n_in,
                              void* d_out, int out_size, void* d_ws, size_t ws_size,
                              hipStream_t stream) {
    const float* x    = (const float*)d_in[0];
    const float* w_ih = (const float*)d_in[1];
    const float* b_ih = (const float*)d_in[2];
    const float* w_hh = (const float*)d_in[3];
    const float* b_hh = (const float*)d_in[4];
    const float* w1   = (const float*)d_in[5];
    const float* w2   = (const float*)d_in[6];
    const float* w_fc = (const float*)d_in[7];
    const float* b_fc = (const float*)d_in[8];

    float* ws = (float*)d_ws;
    unsigned* whh_h = (unsigned*)ws;                         // 32768 u32
    __hip_bfloat16* W2v = (__hip_bfloat16*)(ws + 32768);     // 24576 f worth
    float* G      = ws + 32768 + 24576;                      // 4194304 f
    float* H_all  = G + 4194304;                             // 1048576 f
    // total ~5.30M floats ~= 21.2 MB

    // grid: 1024 gemm tiles + 192 packing blocks (49152 threads)
    gemm_prep<<<1216, 256, 0, stream>>>(x, w_ih, b_ih, w_hh, b_hh, w1,
                                        W2v, whh_h, G);

    lstm_fused<<<Bsz, 512, 0, stream>>>(G, whh_h, W2v, w1, w2, w_fc, b_fc,
                                        H_all, (float*)d_out);
}

// Round 16
// 311.708 us; speedup vs baseline: 1.1286x; 1.1286x over previous
//
#include <hip/hip_runtime.h>
#include <hip/hip_bf16.h>

// Problem: B=32, T=256, I=128, H=128, C=100. All fp32.
// out = (h_T + attn_c_final) @ w_fc.T + b_fc; only the LAST step's attention
// matters (scan carry overwrites attn_c each step).
//
// Structure (r14, measured 309.9us = session best): 2 dispatches.
//  1. gemm_prep (grid 1408 x 256):
//     blocks 0..1023:   G = x @ W_ih^T + (b_ih+b_hh), MFMA split-bf16,
//                       w_ih converted to hi/lo fragments IN-REGISTER.
//     blocks 1024..1407: pack whh_pk + W2v for dispatch 2.
//  2. lstm_fused (32 x 512): r2's 201us recurrence (asm pk_fma + raw
//     lgkm-only barrier) + in-block attention tail (~22us).
//
// Final accounting (all measured): 201 recurrence wall + 22 tail + ~15
// gemm_prep + ~70 fixed harness = ~310.
// Recurrence wall evidence (r0-r15): asm pk_fma 201 < fmaf 239 < dot2 262
// < MFMA 328; restructures (waves_per_eu r1, 8-lane r6) also lose. Wall =
// VALU issue (~520) + AGPR-copy tax (~550: allocator parks 128 weight
// floats in AGPRs at every block shape tried; no VALU op sources AGPRs,
// r4 assembler proof; v_dot2 not full-rate, r15) + latency/barrier (~800)
// at 2 waves/SIMD.

#define Bsz 32
#define Tsz 256
#define Isz 128
#define Hsz 128
#define Csz 100
#define G4H 512   // 4*H

typedef short v8s __attribute__((ext_vector_type(8)));   // 8 bf16 = 4 VGPRs
typedef float v4fa __attribute__((ext_vector_type(4)));  // MFMA acc

// ---------------- device helpers ----------------
__device__ __forceinline__ float2 pk_fma(float2 a, float2 b, float2 c) {
    float2 d;
    asm("v_pk_fma_f32 %0, %1, %2, %3" : "=v"(d) : "v"(a), "v"(b), "v"(c));
    return d;
}
__device__ __forceinline__ float quad_rsum(float x) {
    int t = __builtin_amdgcn_update_dpp(0, __float_as_int(x), 0xB1, 0xF, 0xF, true); // xor 1
    x += __int_as_float(t);
    t = __builtin_amdgcn_update_dpp(0, __float_as_int(x), 0x4E, 0xF, 0xF, true);     // xor 2
    x += __int_as_float(t);
    return x;
}
// 8-lane sum within aligned 8-lane groups: xor1, xor2, half-row mirror
__device__ __forceinline__ float oct_rsum(float x) {
    int t = __builtin_amdgcn_update_dpp(0, __float_as_int(x), 0xB1, 0xF, 0xF, true);
    x += __int_as_float(t);
    t = __builtin_amdgcn_update_dpp(0, __float_as_int(x), 0x4E, 0xF, 0xF, true);
    x += __int_as_float(t);
    t = __builtin_amdgcn_update_dpp(0, __float_as_int(x), 0x141, 0xF, 0xF, true);
    x += __int_as_float(t);
    return x;
}
__device__ __forceinline__ float rcpf(float x) { return __builtin_amdgcn_rcpf(x); }
__device__ __forceinline__ float ex2(float x) { return __builtin_amdgcn_exp2f(x); }
__device__ __forceinline__ float sigm_n(float x) {
    return rcpf(1.0f + ex2(-1.442695041f * x));
}
__device__ __forceinline__ float tanh_n(float x) {
    return fmaf(-2.0f, rcpf(1.0f + ex2(2.885390082f * x)), 1.0f);
}
__device__ __forceinline__ short bf16_bits(float x) {
    __hip_bfloat16 h = __float2bfloat16(x);
    return *reinterpret_cast<short*>(&h);
}
__device__ __forceinline__ float bf16_val(float x) {
    return __bfloat162float(__float2bfloat16(x));
}

// ---------------- kernel 1: fused gemmG + prep ----------------
// blocks < 1024: one 64x64 tile of G = x @ w_ih^T + (b_ih + b_hh).
//   A (x rows) AND B (w_ih rows) both converted fp32 -> hi/lo bf16 frags
//   in-register. 12 k-steps: ks0-3 A_hi*B_hi, 4-7 A_hi*B_lo, 8-11 A_lo*B_hi.
// blocks >= 1024: element-wise packing of whh_pk and W2v.
__global__ __launch_bounds__(256) void gemm_prep(
    const float* __restrict__ x, const float* __restrict__ w_ih,
    const float* __restrict__ b_ih, const float* __restrict__ w_hh,
    const float* __restrict__ b_hh, const float* __restrict__ w1,
    __hip_bfloat16* __restrict__ W2v, float* __restrict__ whh_pk,
    float* __restrict__ G) {
    const int bid = blockIdx.x;
    const int tid = threadIdx.x;

    if (bid >= 1024) {
        int idx = (bid - 1024) * 256 + tid;        // 0..98303
        if (idx < 65536) {
            // whh_pk: r2 lstm layout (float4-coalesced per-thread slices)
            int j4  = idx & 3;
            int q   = (idx >> 2) & 3;
            int d   = (idx >> 4) & 127;
            int gi  = (idx >> 11) & 3;
            int kk4 = (idx >> 13) & 7;
            whh_pk[idx] = w_hh[(size_t)((gi << 7) + d) * 128 + (q << 5) + (kk4 << 2) + j4];
        } else if (idx < 65536 + 16384) {
            int t = idx - 65536;
            int n = t >> 7;            // output col of KV
            int k = t & 127;
            float v = w1[(size_t)(128 + k) * Hsz + n];
            __hip_bfloat16 hi = __float2bfloat16(v);
            __hip_bfloat16 lo = __float2bfloat16(v - __bfloat162float(hi));
            W2v[(size_t)n * 384 + k] = hi;
            W2v[(size_t)n * 384 + 128 + k] = lo;
            W2v[(size_t)n * 384 + 256 + k] = hi;
        }
        return;
    }

    // ---- gemmG tile: m-tile = bid>>3, n-tile = bid&7
    const int w = tid >> 6, lane = tid & 63;
    const int m0 = (bid >> 3) * 64 + (w & 1) * 32;
    const int n0 = (bid & 7) * 64 + (w >> 1) * 32;
    const int r = lane & 15, quad = lane >> 4;

    v8s Ahi[2][4], Alo[2][4];
    #pragma unroll
    for (int i = 0; i < 2; ++i)
        #pragma unroll
        for (int cb = 0; cb < 4; ++cb) {
            const float* src = x + (size_t)(m0 + 16 * i + r) * Isz + cb * 32 + quad * 8;
            float4 f0 = *(const float4*)src;
            float4 f1 = *(const float4*)(src + 4);
            float f[8] = {f0.x, f0.y, f0.z, f0.w, f1.x, f1.y, f1.z, f1.w};
            v8s hi, lo;
            #pragma unroll
            for (int e = 0; e < 8; ++e) {
                float hv = bf16_val(f[e]);
                hi[e] = bf16_bits(f[e]);
                lo[e] = bf16_bits(f[e] - hv);
            }
            Ahi[i][cb] = hi;
            Alo[i][cb] = lo;
        }

    v8s Bhi[2][4], Blo[2][4];    // j: n-subtile (n0+16j+r row of w_ih)
    #pragma unroll
    for (int j = 0; j < 2; ++j)
        #pragma unroll
        for (int cb = 0; cb < 4; ++cb) {
            const float* src = w_ih + (size_t)(n0 + 16 * j + r) * Isz + cb * 32 + quad * 8;
            float4 f0 = *(const float4*)src;
            float4 f1 = *(const float4*)(src + 4);
            float f[8] = {f0.x, f0.y, f0.z, f0.w, f1.x, f1.y, f1.z, f1.w};
            v8s hi, lo;
            #pragma unroll
            for (int e = 0; e < 8; ++e) {
                float hv = bf16_val(f[e]);
                hi[e] = bf16_bits(f[e]);
                lo[e] = bf16_bits(f[e] - hv);
            }
            Bhi[j][cb] = hi;
            Blo[j][cb] = lo;
        }

    v4fa acc[2][2] = {};
    #pragma unroll
    for (int ks = 0; ks < 12; ++ks) {
        int cb = ks & 3;
        bool blo = (ks >= 4) && (ks < 8);
        v8s a0 = (ks >= 8) ? Alo[0][cb] : Ahi[0][cb];
        v8s a1 = (ks >= 8) ? Alo[1][cb] : Ahi[1][cb];
        v8s b0 = blo ? Blo[0][cb] : Bhi[0][cb];
        v8s b1 = blo ? Blo[1][cb] : Bhi[1][cb];
        acc[0][0] = __builtin_amdgcn_mfma_f32_16x16x32_bf16(a0, b0, acc[0][0], 0, 0, 0);
        acc[0][1] = __builtin_amdgcn_mfma_f32_16x16x32_bf16(a0, b1, acc[0][1], 0, 0, 0);
        acc[1][0] = __builtin_amdgcn_mfma_f32_16x16x32_bf16(a1, b0, acc[1][0], 0, 0, 0);
        acc[1][1] = __builtin_amdgcn_mfma_f32_16x16x32_bf16(a1, b1, acc[1][1], 0, 0, 0);
    }
    // C/D layout: col = lane&15, row = quad*4 + reg  [verified m89/m91]
    #pragma unroll
    for (int i = 0; i < 2; ++i)
        #pragma unroll
        for (int j = 0; j < 2; ++j) {
            int cn = n0 + 16 * j + r;
            float bb = b_ih[cn] + b_hh[cn];
            #pragma unroll
            for (int rr = 0; rr < 4; ++rr) {
                int row = m0 + 16 * i + quad * 4 + rr;
                G[(size_t)row * G4H + cn] = acc[i][j][rr] + bb;
            }
        }
}

// ---------------- kernel 2: sequential LSTM + fused attention tail ----------------
// Byte-identical to r11/r14's measured 222.6-223.7us kernel.
#define HPAD(k) ((k) + 8 * ((k) >> 5))

__global__ __launch_bounds__(512, 2) void lstm_fused(
    const float* __restrict__ G, const float* __restrict__ whh_pk,
    const __hip_bfloat16* __restrict__ W2v,
    const float* __restrict__ w1, const float* __restrict__ w2,
    const float* __restrict__ w_fc, const float* __restrict__ b_fc,
    float* __restrict__ H_all, float* __restrict__ out) {
    const int b = blockIdx.x;
    const int tid = threadIdx.x;
    const int d = tid >> 2;
    const int q = tid & 3;

    __shared__ float h_s[2][160];
    __shared__ float kv_s[64][132];
    __shared__ float hT_s[Hsz];
    __shared__ float q_s[Hsz];
    __shared__ float w2s[Hsz];
    __shared__ float r_s[Hsz];
    __shared__ float s_s[64];
    __shared__ float part4[4][Hsz];

    // ================= recurrence (r2 structure, 201us) =================
    float2 w2v[4][16];
    {
        const float4* wp = (const float4*)whh_pk;
        #pragma unroll
        for (int kk4 = 0; kk4 < 8; ++kk4)
            #pragma unroll
            for (int gi = 0; gi < 4; ++gi) {
                float4 v = wp[((kk4 * 4 + gi) * 128 + d) * 4 + q];
                w2v[gi][kk4 * 2]     = make_float2(v.x, v.y);
                w2v[gi][kk4 * 2 + 1] = make_float2(v.z, v.w);
            }
    }

    if (tid < 320) ((float*)h_s)[tid] = 0.0f;
    float c = 0.0f;
    __syncthreads();   // once, before the loop: full drain is fine here

    const float* Gq = G + (size_t)b * Tsz * G4H + q * 128 + d;
    float* Hst = H_all + (size_t)b * Tsz * Hsz + d;

    float gval = Gq[0];
    int cur = 0;
    for (int t = 0; t < Tsz; ++t) {
        const int tn = (t < Tsz - 1) ? t + 1 : t;
        float ngval = Gq[(size_t)tn * G4H];   // prefetch; stays in flight
                                              // across the raw barrier

        float2 accA[4], accB[4];
        #pragma unroll
        for (int gi = 0; gi < 4; ++gi) {
            accA[gi] = make_float2(q == gi ? gval : 0.f, 0.f);
            accB[gi] = make_float2(0.f, 0.f);
        }
        const float4* hb4 = (const float4*)&h_s[cur][q * 40];  // HPAD(q*32)=q*40
        #pragma unroll
        for (int kk4 = 0; kk4 < 8; ++kk4) {
            float4 h4 = hb4[kk4];
            float2 hA = make_float2(h4.x, h4.y);
            float2 hB = make_float2(h4.z, h4.w);
            accA[0] = pk_fma(hA, w2v[0][2 * kk4], accA[0]);
            accA[1] = pk_fma(hA, w2v[1][2 * kk4], accA[1]);
            accA[2] = pk_fma(hA, w2v[2][2 * kk4], accA[2]);
            accA[3] = pk_fma(hA, w2v[3][2 * kk4], accA[3]);
            accB[0] = pk_fma(hB, w2v[0][2 * kk4 + 1], accB[0]);
            accB[1] = pk_fma(hB, w2v[1][2 * kk4 + 1], accB[1]);
            accB[2] = pk_fma(hB, w2v[2][2 * kk4 + 1], accB[2]);
            accB[3] = pk_fma(hB, w2v[3][2 * kk4 + 1], accB[3]);
        }
        float a0 = quad_rsum(accA[0].x + accA[0].y + accB[0].x + accB[0].y);
        float a1 = quad_rsum(accA[1].x + accA[1].y + accB[1].x + accB[1].y);
        float a2 = quad_rsum(accA[2].x + accA[2].y + accB[2].x + accB[2].y);
        float a3 = quad_rsum(accA[3].x + accA[3].y + accB[3].x + accB[3].y);

        float iv = sigm_n(a0);
        float fv = sigm_n(a1);
        float gv = tanh_n(a2);
        float ov = sigm_n(a3);
        c = fmaf(fv, c, iv * gv);
        float h = ov * tanh_n(c);

        if (q == 0) {
            h_s[cur ^ 1][HPAD(d)] = h;
            Hst[(size_t)t * Hsz] = h;
        }
        gval = ngval;
        // ---- raw barrier: wait LDS only, leave global load/store in flight
        __builtin_amdgcn_sched_barrier(0);
        asm volatile("s_waitcnt lgkmcnt(0)" ::: "memory");
        __builtin_amdgcn_s_barrier();
        __builtin_amdgcn_sched_barrier(0);
        cur ^= 1;
    }

    // ================= fused attention tail =================
    __syncthreads();   // full drain: H_all stores visible block-locally

    const float* Hb = H_all + (size_t)b * Tsz * Hsz;
    const int n_a = tid >> 2;

    // Phase A: q_s = hT @ w1_top; stage hT and w2 in LDS
    {
        if (tid < Hsz) {
            hT_s[tid] = h_s[cur][HPAD(tid)];
            w2s[tid] = w2[tid];
        }
        float acc = 0.f;
        #pragma unroll 8
        for (int kk = 0; kk < 32; ++kk) {
            int k = q * 32 + kk;
            acc = fmaf(h_s[cur][HPAD(k)], w1[(size_t)k * Hsz + n_a], acc);
        }
        acc = quad_rsum(acc);
        if (q == 0) q_s[n_a] = acc;
    }
    __syncthreads();

    // Phase B: 4 jt-tiles of 64 slots: KV (MFMA) -> scores -> attn partial
    const int w_id = tid >> 6;
    const int lane = tid & 63;
    const int fr = lane & 15, fq = lane >> 4;
    const int d_att = tid & 127, grp = tid >> 7;
    float racc = 0.f;

    for (int jt = 0; jt < 4; ++jt) {
        // B1: KV tile rows jt*64..+64, cols 0..128, 8 waves (one 32x32 each)
        {
            const int m0 = (w_id & 1) * 32;
            const int n0 = (w_id >> 1) * 32;
            const float* Abase = Hb + (size_t)(jt * 64) * Hsz;

            v8s Ahi[2][4], Alo[2][4];
            #pragma unroll
            for (int i = 0; i < 2; ++i)
                #pragma unroll
                for (int cb = 0; cb < 4; ++cb) {
                    const float* src = Abase + (size_t)(m0 + 16 * i + fr) * Hsz + cb * 32 + fq * 8;
                    float4 f0 = *(const float4*)src;
                    float4 f1 = *(const float4*)(src + 4);
                    float f[8] = {f0.x, f0.y, f0.z, f0.w, f1.x, f1.y, f1.z, f1.w};
                    v8s hi, lo;
                    #pragma unroll
                    for (int e = 0; e < 8; ++e) {
                        float hv = bf16_val(f[e]);
                        hi[e] = bf16_bits(f[e]);
                        lo[e] = bf16_bits(f[e] - hv);
                    }
                    Ahi[i][cb] = hi;
                    Alo[i][cb] = lo;
                }

            v4fa a2[2][2] = {};
            const short* Wb = (const short*)W2v;
            #pragma unroll
            for (int ks = 0; ks < 12; ++ks) {
                int cb = ks & 3;
                v8s a0 = (ks >= 8) ? Alo[0][cb] : Ahi[0][cb];
                v8s a1 = (ks >= 8) ? Alo[1][cb] : Ahi[1][cb];
                int kb = ks * 32 + fq * 8;
                v8s b0 = *(const v8s*)(Wb + (size_t)(n0 + fr) * 384 + kb);
                v8s b1 = *(const v8s*)(Wb + (size_t)(n0 + 16 + fr) * 384 + kb);
                a2[0][0] = __builtin_amdgcn_mfma_f32_16x16x32_bf16(a0, b0, a2[0][0], 0, 0, 0);
                a2[0][1] = __builtin_amdgcn_mfma_f32_16x16x32_bf16(a0, b1, a2[0][1], 0, 0, 0);
                a2[1][0] = __builtin_amdgcn_mfma_f32_16x16x32_bf16(a1, b0, a2[1][0], 0, 0, 0);
                a2[1][1] = __builtin_amdgcn_mfma_f32_16x16x32_bf16(a1, b1, a2[1][1], 0, 0, 0);
            }
            #pragma unroll
            for (int i = 0; i < 2; ++i)
                #pragma unroll
                for (int j = 0; j < 2; ++j)
                    #pragma unroll
                    for (int rr = 0; rr < 4; ++rr)
                        kv_s[m0 + 16 * i + fq * 4 + rr][n0 + 16 * j + fr] = a2[i][j][rr];
        }
        __syncthreads();

        // B2: scores, one 8-lane group per slot (64 slots)
        {
            const int jl = tid >> 3, oct = tid & 7;
            float p = 0.f;
            #pragma unroll
            for (int kk = 0; kk < 16; ++kk) {
                int k = oct * 16 + kk;
                p = fmaf(tanh_n(q_s[k] + kv_s[jl][k]), w2s[k], p);
            }
            p = oct_rsum(p);
            if (oct == 0) s_s[jl] = (jt * 64 + jl < 255) ? p : 0.0f;
        }
        __syncthreads();

        // B3: attn partial: racc += s[j] * H[j][d] over this tile's 16 j/grp
        #pragma unroll 4
        for (int u = 0; u < 16; ++u) {
            int lj = grp * 16 + u;
            racc = fmaf(s_s[lj], Hb[(size_t)(jt * 64 + lj) * Hsz + d_att], racc);
        }
        __syncthreads();   // protect kv_s / s_s before next jt overwrites
    }

    part4[grp][d_att] = racc;
    __syncthreads();
    if (tid < Hsz)
        r_s[tid] = hT_s[tid] + part4[0][tid] + part4[1][tid] + part4[2][tid] + part4[3][tid];
    __syncthreads();

    // Phase C: out[b] = r @ w_fc^T + b_fc (one quad per output)
    {
        const int o = tid >> 2;
        float acc = 0.f;
        if (o < Csz) {
            #pragma unroll 8
            for (int kk = 0; kk < 32; ++kk) {
                int k = q * 32 + kk;
                acc = fmaf(r_s[k], w_fc[(size_t)o * Hsz + k], acc);
            }
        }
        acc = quad_rsum(acc);
        if (q == 0 && o < Csz) out[b * Csz + o] = acc + b_fc[o];
    }
}

// ---------------- launch ----------------
extern "C" void kernel_launch(void* const* d_in, const int* in_sizes, int n_in,
                              void* d_out, int out_size, void* d_ws, size_t ws_size,
                              hipStream_t stream) {
    const float* x    = (const float*)d_in[0];
    const float* w_ih = (const float*)d_in[1];
    const float* b_ih = (const float*)d_in[2];
    const float* w_hh = (const float*)d_in[3];
    const float* b_hh = (const float*)d_in[4];
    const float* w1   = (const float*)d_in[5];
    const float* w2   = (const float*)d_in[6];
    const float* w_fc = (const float*)d_in[7];
    const float* b_fc = (const float*)d_in[8];

    float* ws = (float*)d_ws;
    float* whh_pk = ws;                                      // 65536 f
    __hip_bfloat16* W2v = (__hip_bfloat16*)(whh_pk + 65536); // 24576 f worth
    float* G      = whh_pk + 65536 + 24576;                  // 4194304 f
    float* H_all  = G + 4194304;                             // 1048576 f
    // total ~5.33M floats ~= 21.3 MB

    gemm_prep<<<1408, 256, 0, stream>>>(x, w_ih, b_ih, w_hh, b_hh, w1,
                                        W2v, whh_pk, G);

    lstm_fused<<<Bsz, 512, 0, stream>>>(G, whh_pk, W2v, w1, w2, w_fc, b_fc,
                                        H_all, (float*)d_out);
}